// Round 17
// baseline (131.047 us; speedup 1.0000x reference)
//
#include <hip/hip_runtime.h>
#include <hip/hip_fp16.h>
#include <math.h>

typedef _Float16 f16;
typedef _Float16 f16x4 __attribute__((ext_vector_type(4)));
typedef _Float16 f16x8 __attribute__((ext_vector_type(8)));
typedef float f32x4 __attribute__((ext_vector_type(4)));

#define MFMA16(a, b, c) __builtin_amdgcn_mfma_f32_16x16x32_f16((a), (b), (c), 0, 0, 0)

static constexpr float SW_W    = 1024.f;              // weight scale (exact pow2)
static constexpr float SA_A    = 64.f;                // main-loop activation scale
static constexpr float INV_SW  = 1.f / 1024.f;
static constexpr float INV_SW2 = 1.f / (1024.f * 1024.f);
static constexpr float INV_SASW = 1.f / (64.f * 1024.f);

// workspace layout (bytes)
static constexpr size_t OFF_CY = 0;                         // 128*128 f32
static constexpr size_t OFF_CX = OFF_CY + 65536;
static constexpr size_t OFF_LW = OFF_CX + 65536;            // 512*8 f16 frag-ordered last1_w*SW
static constexpr size_t OFF_S  = OFF_LW + 8192;             // 256 f32 rowsum(wfine)
static constexpr size_t OFF_CW = OFF_S  + 1024;             // 1088*1024 f16 conv_w*SW (padded)
static constexpr size_t OFF_M2 = OFF_CW + (size_t)1088 * 1024 * 2;  // 8*256*1024 f16  M2T[b][j][c]
static constexpr size_t OFF_W  = OFF_M2 + (size_t)8 * 256 * 1024 * 2; // 8*1028*256 f32
static constexpr size_t OFF_AY = OFF_W  + (size_t)8 * 1028 * 256 * 4; // 8*128*256 f16
static constexpr size_t OFF_BX = OFF_AY + (size_t)8 * 128 * 256 * 2;  // 8*128*256 f16
static constexpr size_t OFF_WT = OFF_BX + (size_t)8 * 128 * 256 * 2;  // 8*3*65536 f16 frag wj*SW

static __device__ inline f32x4 zero4() { f32x4 v = {0.f, 0.f, 0.f, 0.f}; return v; }

// ---- K1: gemmA (blocks 0..511) | PE tables + lwf (512..641) | conv_w cast (642..1185) | S (1186) ----
__global__ __launch_bounds__(256, 4) void k_prepA(
    const float* __restrict__ x, const float* __restrict__ wfine,
    f16* __restrict__ M2,
    float* __restrict__ cy, float* __restrict__ cx,
    f16* __restrict__ lwf, const float* __restrict__ lw,
    const float* __restrict__ cw, f16* __restrict__ cw16,
    float* __restrict__ S)
{
    __shared__ __align__(16) f16 Ab[2][64 * 32];
    __shared__ __align__(16) f16 Bb[2][64 * 32];
    const int bid = blockIdx.x;
    const int t = threadIdx.x;
    if (bid < 512) {
        const int lane = t & 63;
        const int wc = t >> 6;
        const int nlo = lane & 15, q4 = lane >> 4;
        const int b = bid >> 6, rem = bid & 63;
        const int jt = rem >> 4, ct = rem & 15;
        const int j0 = jt << 6, c0 = ct << 6;

        auto stageA = [&](int buf, int k0) {        // x rows (c) -> f16
            const float* src = x + (((size_t)((b << 10) + c0 + (t >> 2))) << 8) + k0 + ((t & 3) << 3);
            f16x8 v;
            #pragma unroll
            for (int i = 0; i < 8; i++) v[i] = (f16)src[i];
            *(f16x8*)(&Ab[buf][t << 3]) = v;
        };
        auto stageB = [&](int buf, int k0) {        // wfine rows (j) -> f16 *SW
            const float* src = wfine + (size_t)(j0 + (t >> 2)) * 256 + k0 + ((t & 3) << 3);
            f16x8 v;
            #pragma unroll
            for (int i = 0; i < 8; i++) v[i] = (f16)(src[i] * SW_W);
            *(f16x8*)(&Bb[buf][t << 3]) = v;
        };

        f32x4 acc[4];
        #pragma unroll
        for (int mt = 0; mt < 4; mt++) acc[mt] = zero4();

        stageA(0, 0); stageB(0, 0);
        __syncthreads();
        for (int c = 0; c < 8; c++) {
            const int cb = c & 1;
            if (c + 1 < 8) { stageA(cb ^ 1, (c + 1) << 5); stageB(cb ^ 1, (c + 1) << 5); }
            f16x8 af[4], bf;
            bf = *(const f16x8*)(&Bb[cb][(((wc << 4) + nlo) << 5) + (q4 << 3)]);
            #pragma unroll
            for (int mt = 0; mt < 4; mt++)
                af[mt] = *(const f16x8*)(&Ab[cb][(((mt << 4) + nlo) << 5) + (q4 << 3)]);
            #pragma unroll
            for (int mt = 0; mt < 4; mt++)
                acc[mt] = MFMA16(af[mt], bf, acc[mt]);
            __syncthreads();
        }
        const int j = j0 + (wc << 4) + nlo;
        #pragma unroll
        for (int mt = 0; mt < 4; mt++) {
            const int cc = c0 + (mt << 4) + (q4 << 2);
            f16x4 pk;
            #pragma unroll
            for (int i = 0; i < 4; i++) pk[i] = (f16)acc[mt][i];
            *(f16x4*)(M2 + (((size_t)((b << 8) + j)) << 10) + cc) = pk;
        }
        return;
    }
    if (bid < 642) {
        int id = (bid - 512) * 256 + t;
        const float r = 1.99999f / 256.f;
        if (id < 32768) {
            float* dst = (id < 16384) ? cy : cx;
            int e = id & 16383;
            int row = e >> 7, f = e & 127;
            float s = -0.99999f + r + 2.f * r * (float)row;
            float coef = 6.283185307179586f * powf(10.f, (float)(f & 63) * (1.f / 64.f));
            float arg = coef * s;
            dst[e] = (f < 64) ? cosf(arg) : sinf(arg);
        } else {
            int id2 = id - 32768;           // 512 entries: frag-ordered last1_w
            int c = id2 >> 6, lane = id2 & 63;
            int nlo = lane & 15, q4 = lane >> 4;
            f16x8 v;
            #pragma unroll
            for (int ko = 0; ko < 8; ko++)
                v[ko] = (nlo < 3) ? (f16)(lw[nlo * 256 + (c << 5) + (q4 << 3) + ko] * SW_W) : (f16)0.f;
            *(f16x8*)(lwf + id2 * 8) = v;
        }
        return;
    }
    if (bid < 1186) {
        // conv_w (1028x1024 f32) -> cw16 (1088x1024 f16 *SW, zero-padded rows)
        const int g8 = (bid - 642) * 256 + t;
        const int row = g8 >> 7, col0 = (g8 & 127) << 3;
        f16x8 v;
        if (row < 1028) {
            const float* src = cw + (size_t)row * 1024 + col0;
            #pragma unroll
            for (int i = 0; i < 8; i++) v[i] = (f16)(src[i] * SW_W);
        } else {
            #pragma unroll
            for (int i = 0; i < 8; i++) v[i] = (f16)0.f;
        }
        *(f16x8*)(cw16 + (size_t)g8 * 8) = v;
        return;
    }
    {
        // S[j] = sum_k wfine[j,k]
        const float* src = wfine + (size_t)t * 256;
        float s = 0.f;
        for (int k = 0; k < 256; k += 4) {
            const f32x4 v = *(const f32x4*)(src + k);
            s += (v[0] + v[1]) + (v[2] + v[3]);
        }
        S[t] = s;
    }
}

// ---- GEMM-B: W[b][i][j] = (sum_c cw16[i,c]*M2T[b,j,c])/2^20 + conv_b[i]*S[j] + wfine_b[j] ----
__global__ __launch_bounds__(256, 4) void k_gemmB(
    const f16* __restrict__ cw16, const f16* __restrict__ M2,
    const float* __restrict__ conv_b, const float* __restrict__ S,
    const float* __restrict__ wfine_b, float* __restrict__ W)
{
    __shared__ __align__(16) f16 Ab[2][64 * 32];
    __shared__ __align__(16) f16 Bb[2][64 * 32];
    const int t = threadIdx.x;
    const int lane = t & 63;
    const int wc = t >> 6;
    const int nlo = lane & 15, q4 = lane >> 4;
    const int blk = blockIdx.x;                 // 544 = 8b * 17it * 4jt
    const int b = blk / 68, rem = blk % 68;
    const int it = rem >> 2, jt = rem & 3;
    const int i0 = it << 6, j0 = jt << 6;

    auto stageA = [&](int buf, int k0) {        // M2T rows (j)
        *(f16x8*)(&Ab[buf][t << 3]) =
            *(const f16x8*)(M2 + (((size_t)((b << 8) + j0 + (t >> 2))) << 10) + k0 + ((t & 3) << 3));
    };
    auto stageB = [&](int buf, int k0) {        // cw16 rows (i, padded)
        *(f16x8*)(&Bb[buf][t << 3]) =
            *(const f16x8*)(cw16 + (((size_t)(i0 + (t >> 2))) << 10) + k0 + ((t & 3) << 3));
    };

    f32x4 acc[4];
    #pragma unroll
    for (int mt = 0; mt < 4; mt++) acc[mt] = zero4();

    stageA(0, 0); stageB(0, 0);
    __syncthreads();
    for (int c = 0; c < 32; c++) {
        const int cb = c & 1;
        if (c + 1 < 32) { stageA(cb ^ 1, (c + 1) << 5); stageB(cb ^ 1, (c + 1) << 5); }
        f16x8 af[4], bf;
        bf = *(const f16x8*)(&Bb[cb][(((wc << 4) + nlo) << 5) + (q4 << 3)]);
        #pragma unroll
        for (int mt = 0; mt < 4; mt++)
            af[mt] = *(const f16x8*)(&Ab[cb][(((mt << 4) + nlo) << 5) + (q4 << 3)]);
        #pragma unroll
        for (int mt = 0; mt < 4; mt++)
            acc[mt] = MFMA16(af[mt], bf, acc[mt]);
        __syncthreads();
    }
    const int i = i0 + (wc << 4) + nlo;
    if (i < 1028) {
        const float cbv = conv_b[i];
        #pragma unroll
        for (int mt = 0; mt < 4; mt++) {
            const int j = j0 + (mt << 4) + (q4 << 2);
            const f32x4 sv = *(const f32x4*)(S + j);
            const f32x4 wb = *(const f32x4*)(wfine_b + j);
            f32x4 o;
            #pragma unroll
            for (int ii = 0; ii < 4; ii++)
                o[ii] = acc[mt][ii] * INV_SW2 + cbv * sv[ii] + wb[ii];
            *(f32x4*)(W + (((size_t)(b * 1028 + i)) << 8) + j) = o;
        }
    }
}

// ---- merged: axby (blocks 0..255) + castw fragment-order (blocks 256..639) ----
__global__ void k_wprep(const float* __restrict__ cy, const float* __restrict__ cx,
                        const float* __restrict__ W, f16* __restrict__ ayF,
                        f16* __restrict__ bxF, f16* __restrict__ wjT)
{
    __shared__ float tile[64][65];
    const int bid = blockIdx.x;
    const int t = threadIdx.x;
    if (bid < 256) {
        const int b = bid >> 5, which = (bid >> 4) & 1, rtile = bid & 15;
        const int r0 = rtile << 3;
        const float* ctab = which ? cx : cy;
        const float* Wb = W + (size_t)(b * 1028 + (which ? 128 : 0)) * 256;
        float acc[8];
        #pragma unroll
        for (int r = 0; r < 8; r++) acc[r] = 0.f;
        for (int k = 0; k < 128; k++) {
            const float wv = Wb[(k << 8) + t];
            #pragma unroll
            for (int r = 0; r < 8; r++)
                acc[r] = fmaf(ctab[((r0 + r) << 7) + k], wv, acc[r]);
        }
        const float b1v = which ? 0.f : W[(size_t)(b * 1028 + 256) * 256 + t];
        f16* dst = which ? bxF : ayF;
        for (int r = 0; r < 8; r++)
            dst[(size_t)((b << 7) + r0 + r) * 256 + t] = (f16)((acc[r] + b1v) * SA_A);
        return;
    }
    const int id = bid - 256;                  // 384 = 8b * 3jj * 16 tiles
    const int b = id / 48;
    const int rr = id % 48;
    const int jj = rr / 16;
    const int tt = rr % 16;
    const int kt = tt >> 2, wt = tt & 3;
    const int k0 = kt << 6, n0 = wt << 6;
    const float* src = W + (size_t)(b * 1028 + 257 * (jj + 1)) * 256;
    for (int i = 0; i < 16; i++) {
        int e = i * 256 + t;
        int kk = e >> 6, nn = e & 63;
        tile[kk][nn] = src[(size_t)(k0 + kk) * 256 + n0 + nn];
    }
    __syncthreads();
    f16* dst = wjT + (size_t)(b * 3 + jj) * 65536;
    #pragma unroll
    for (int i = 0; i < 2; i++) {
        const int g = i * 256 + t;
        const int c_rel = g >> 8, sub = g & 255;
        const int nt = sub >> 6, ln = sub & 63;
        const int nl = ln & 15, q4g = ln >> 4;
        f16x8 v;
        #pragma unroll
        for (int ko = 0; ko < 8; ko++)
            v[ko] = (f16)(tile[(c_rel << 5) + (q4g << 3) + ko][(nt << 4) + nl] * SW_W);
        const int c = (kt << 1) + c_rel;
        *(f16x8*)(dst + (size_t)(((((c << 2) | wt) << 2) | nt) << 9) + (ln << 3)) = v;
    }
}

// ---- fused MLP: layers 2..4 + final projection + silu ----
// 128px/block (one image row), 256 thr / 4 waves: each wave computes TWO 64px
// tiles with the SAME weight fragments -> 32 MFMA per weight load (2x latency
// budget, 1/2 L2 weight traffic). acc 128 AGPR + dbuf 64; launch_bounds(256,1)
// gives 512-reg budget (spill-proof); occupancy 1 block/CU by design.
__global__ __launch_bounds__(256, 1) void k_main(
    const f16* __restrict__ wjT, const float* __restrict__ Wfull,
    const f16* __restrict__ ayF, const f16* __restrict__ bxF,
    const f16* __restrict__ lwf, const float* __restrict__ lb,
    const float* __restrict__ pa_p, float* __restrict__ out)
{
    __shared__ __align__(16) unsigned char actS[65536];     // 128px x 256f f16, slot-swizzled
    const int t = threadIdx.x;
    const int lane = t & 63;
    const int wc = t >> 6;
    const int nlo = lane & 15, q4 = lane >> 4;
    const int blk = blockIdx.x;
    const int b = blk & 7, rt = blk >> 3;      // batch = XCD index; rt in [0,128)
    const int p0 = rt << 7;                    // 128 px = one image row
    const int y = rt;
    const float pa = pa_p[0];

    const f16* wl0 = wjT + (size_t)(b * 3) * 65536;
    auto loadBg = [&](f16x8* dstv, int g) {
        const f16* p = wl0 + (size_t)(g >> 3) * 65536 + ((size_t)((((g & 7) << 2) | wc)) << 11) + (lane << 3);
        #pragma unroll
        for (int nt = 0; nt < 4; nt++) dstv[nt] = *(const f16x8*)(p + (nt << 9));
    };
    auto lbar = [&]() {      // LDS-drained barrier; vmem prefetch stays in flight
        asm volatile("s_waitcnt lgkmcnt(0)" ::: "memory");
        __builtin_amdgcn_s_barrier();
        __builtin_amdgcn_sched_barrier(0);
    };

    f16x8 bfA[4], bfB[4];
    loadBg(bfA, 0);          // persistent cross-layer weight double-buffer

    // ---- init act = f16(prelu(ayF[y] + bxF[x])), 128 rows x 32 slots ----
    {
        const int r = t & 127, g8 = t >> 7;    // 2 threads/row, 16 slots each
        const f16* ayr = ayF + (size_t)((b << 7) + y) * 256;
        const f16* bxr = bxF + (size_t)((b << 7) + r) * 256;
        const int rx = r & 7;
        #pragma unroll
        for (int mm = 0; mm < 16; mm++) {
            const int slot = (g8 << 4) + mm;
            const int f0 = slot << 3;
            f16x8 av = *(const f16x8*)(ayr + f0);
            f16x8 bv = *(const f16x8*)(bxr + f0);
            f16x8 v;
            #pragma unroll
            for (int i = 0; i < 8; i++) {
                float hv = (float)av[i] + (float)bv[i];
                hv = fmaxf(hv, 0.f) + pa * fminf(hv, 0.f);
                v[i] = (f16)hv;
            }
            *(f16x8*)(actS + (r << 9) + ((slot ^ rx) << 4)) = v;
        }
    }
    lbar();

    for (int jj = 0; jj < 3; jj++) {
        f32x4 accA[4][4], accB[4][4];
        #pragma unroll
        for (int pt = 0; pt < 4; pt++)
            #pragma unroll
            for (int nt = 0; nt < 4; nt++) { accA[pt][nt] = zero4(); accB[pt][nt] = zero4(); }

        #pragma unroll
        for (int c = 0; c < 8; c++) {
            const int g = jj * 8 + c;
            f16x8* curW = (c & 1) ? bfB : bfA;     // g&1 == c&1 (jj*8 even)
            f16x8* nxtW = (c & 1) ? bfA : bfB;
            if (g < 23) loadBg(nxtW, g + 1);       // crosses layer boundary at c==7
            const int sl = (c << 2) + q4;
            f16x8 afA[4], afB[4];
            #pragma unroll
            for (int pt = 0; pt < 4; pt++) {
                const int rr = (pt << 4) + nlo;    // tile A rows 0..63
                afA[pt] = *(const f16x8*)(actS + (rr << 9) + ((sl ^ (rr & 7)) << 4));
            }
            #pragma unroll
            for (int pt = 0; pt < 4; pt++)
                #pragma unroll
                for (int nt = 0; nt < 4; nt++)
                    accA[pt][nt] = MFMA16(curW[nt], afA[pt], accA[pt][nt]);
            #pragma unroll
            for (int pt = 0; pt < 4; pt++) {
                const int rr = 64 + (pt << 4) + nlo;   // tile B rows 64..127
                afB[pt] = *(const f16x8*)(actS + (rr << 9) + ((sl ^ (rr & 7)) << 4));
            }
            #pragma unroll
            for (int pt = 0; pt < 4; pt++)
                #pragma unroll
                for (int nt = 0; nt < 4; nt++)
                    accB[pt][nt] = MFMA16(curW[nt], afB[pt], accB[pt][nt]);
        }
        lbar();   // all reads of actS done (LDS only; vmem prefetch survives)

        // epilogue: act <- f16(prelu(acc/SW + SA*b_j)) for both tiles
        const float* bias = Wfull + (size_t)(b * 1028 + 257 * (jj + 1) + 256) * 256;
        #pragma unroll
        for (int nt = 0; nt < 4; nt++) {
            const int nb = (wc << 6) + (nt << 4) + (q4 << 2);
            const f32x4 b4 = *(const f32x4*)(bias + nb);
            #pragma unroll
            for (int pt = 0; pt < 4; pt++) {
                const int rrA = (pt << 4) + nlo;
                f16x4 pkA;
                #pragma unroll
                for (int i = 0; i < 4; i++) {
                    float v = fmaf(accA[pt][nt][i], INV_SW, b4[i] * SA_A);
                    v = fmaxf(v, 0.f) + pa * fminf(v, 0.f);
                    pkA[i] = (f16)v;
                }
                *(f16x4*)(actS + (rrA << 9) + (((nb >> 3) ^ (rrA & 7)) << 4) + ((nb & 7) << 1)) = pkA;
                const int rrB = 64 + rrA;
                f16x4 pkB;
                #pragma unroll
                for (int i = 0; i < 4; i++) {
                    float v = fmaf(accB[pt][nt][i], INV_SW, b4[i] * SA_A);
                    v = fmaxf(v, 0.f) + pa * fminf(v, 0.f);
                    pkB[i] = (f16)v;
                }
                *(f16x4*)(actS + (rrB << 9) + (((nb >> 3) ^ (rrB & 7)) << 4) + ((nb & 7) << 1)) = pkB;
            }
        }
        lbar();
    }

    // ---- final 256->3 projection + silu: each wave owns 32 px (2 x 16) ----
    #pragma unroll
    for (int gi = 0; gi < 2; gi++) {
        f32x4 acc2 = zero4();
        const int rr = (wc << 5) + (gi << 4) + nlo;
        #pragma unroll
        for (int c = 0; c < 8; c++) {
            const int sl = (c << 2) + q4;
            const f16x8 af = *(const f16x8*)(actS + (rr << 9) + ((sl ^ (rr & 7)) << 4));
            const f16x8 lf = *(const f16x8*)(lwf + (((c << 6) + lane) << 3));
            acc2 = MFMA16(af, lf, acc2);
        }
        if (nlo < 3) {
            const float lbv = lb[nlo];
            float* ob = out + ((size_t)(b * 3 + nlo) << 14) + p0 + (wc << 5) + (gi << 4) + (q4 << 2);
            #pragma unroll
            for (int i = 0; i < 4; i++) {
                float z = acc2[i] * INV_SASW + lbv;
                ob[i] = z / (1.f + expf(-z));
            }
        }
    }
}

extern "C" void kernel_launch(void* const* d_in, const int* in_sizes, int n_in,
                              void* d_out, int out_size, void* d_ws, size_t ws_size,
                              hipStream_t stream)
{
    (void)in_sizes; (void)n_in; (void)out_size; (void)ws_size;
    const float* x       = (const float*)d_in[0];
    const float* conv_w  = (const float*)d_in[1];
    const float* conv_b  = (const float*)d_in[2];
    const float* wfine_w = (const float*)d_in[3];
    const float* wfine_b = (const float*)d_in[4];
    const float* last1_w = (const float*)d_in[5];
    const float* last1_b = (const float*)d_in[6];
    const float* prelu_a = (const float*)d_in[7];
    char* ws = (char*)d_ws;
    float* Cy  = (float*)(ws + OFF_CY);
    float* Cx  = (float*)(ws + OFF_CX);
    f16*   lwf = (f16*)(ws + OFF_LW);
    float* S   = (float*)(ws + OFF_S);
    f16*   cw16= (f16*)(ws + OFF_CW);
    f16*   M2  = (f16*)(ws + OFF_M2);
    float* W   = (float*)(ws + OFF_W);
    f16*   AyF = (f16*)(ws + OFF_AY);
    f16*   BxF = (f16*)(ws + OFF_BX);
    f16*   wjT = (f16*)(ws + OFF_WT);

    k_prepA<<<1187, 256, 0, stream>>>(x, wfine_w, M2, Cy, Cx, lwf, last1_w, conv_w, cw16, S);
    k_gemmB<<<544, 256, 0, stream>>>(cw16, M2, conv_b, S, wfine_b, W);
    k_wprep<<<640, 256, 0, stream>>>(Cy, Cx, W, AyF, BxF, wjT);
    k_main<<<1024, 256, 0, stream>>>(wjT, W, AyF, BxF, lwf, last1_b, prelu_a, (float*)d_out);
}

// Round 18
// 114.687 us; speedup vs baseline: 1.1426x; 1.1426x over previous
//
#include <hip/hip_runtime.h>
#include <hip/hip_fp16.h>
#include <math.h>

typedef _Float16 f16;
typedef _Float16 f16x4 __attribute__((ext_vector_type(4)));
typedef _Float16 f16x8 __attribute__((ext_vector_type(8)));
typedef float f32x4 __attribute__((ext_vector_type(4)));

#define MFMA16(a, b, c) __builtin_amdgcn_mfma_f32_16x16x32_f16((a), (b), (c), 0, 0, 0)

static constexpr float SW_W    = 1024.f;              // weight scale (exact pow2)
static constexpr float SA_A    = 64.f;                // main-loop activation scale
static constexpr float INV_SW  = 1.f / 1024.f;
static constexpr float INV_SW2 = 1.f / (1024.f * 1024.f);
static constexpr float INV_SASW = 1.f / (64.f * 1024.f);

// workspace layout (bytes)
static constexpr size_t OFF_CY = 0;                         // 128*128 f32
static constexpr size_t OFF_CX = OFF_CY + 65536;
static constexpr size_t OFF_LW = OFF_CX + 65536;            // 512*8 f16 frag-ordered last1_w*SW
static constexpr size_t OFF_S  = OFF_LW + 8192;             // 256 f32 rowsum(wfine)
static constexpr size_t OFF_CW = OFF_S  + 1024;             // 1088*1024 f16 conv_w*SW (padded)
static constexpr size_t OFF_M2 = OFF_CW + (size_t)1088 * 1024 * 2;  // 8*256*1024 f16  M2T[b][j][c]
static constexpr size_t OFF_W  = OFF_M2 + (size_t)8 * 256 * 1024 * 2; // 8*1028*256 f32
static constexpr size_t OFF_AY = OFF_W  + (size_t)8 * 1028 * 256 * 4; // 8*128*256 f16
static constexpr size_t OFF_BX = OFF_AY + (size_t)8 * 128 * 256 * 2;  // 8*128*256 f16
static constexpr size_t OFF_WT = OFF_BX + (size_t)8 * 128 * 256 * 2;  // 8*3*65536 f16 frag wj*SW

static __device__ inline f32x4 zero4() { f32x4 v = {0.f, 0.f, 0.f, 0.f}; return v; }

// ---- K1: gemmA (blocks 0..511) | PE tables + lwf (512..641) | conv_w cast (642..1185) | S (1186) ----
__global__ __launch_bounds__(256, 4) void k_prepA(
    const float* __restrict__ x, const float* __restrict__ wfine,
    f16* __restrict__ M2,
    float* __restrict__ cy, float* __restrict__ cx,
    f16* __restrict__ lwf, const float* __restrict__ lw,
    const float* __restrict__ cw, f16* __restrict__ cw16,
    float* __restrict__ S)
{
    __shared__ __align__(16) f16 Ab[2][64 * 32];
    __shared__ __align__(16) f16 Bb[2][64 * 32];
    const int bid = blockIdx.x;
    const int t = threadIdx.x;
    if (bid < 512) {
        const int lane = t & 63;
        const int wc = t >> 6;
        const int nlo = lane & 15, q4 = lane >> 4;
        const int b = bid >> 6, rem = bid & 63;
        const int jt = rem >> 4, ct = rem & 15;
        const int j0 = jt << 6, c0 = ct << 6;

        auto stageA = [&](int buf, int k0) {        // x rows (c) -> f16
            const float* src = x + (((size_t)((b << 10) + c0 + (t >> 2))) << 8) + k0 + ((t & 3) << 3);
            f16x8 v;
            #pragma unroll
            for (int i = 0; i < 8; i++) v[i] = (f16)src[i];
            *(f16x8*)(&Ab[buf][t << 3]) = v;
        };
        auto stageB = [&](int buf, int k0) {        // wfine rows (j) -> f16 *SW
            const float* src = wfine + (size_t)(j0 + (t >> 2)) * 256 + k0 + ((t & 3) << 3);
            f16x8 v;
            #pragma unroll
            for (int i = 0; i < 8; i++) v[i] = (f16)(src[i] * SW_W);
            *(f16x8*)(&Bb[buf][t << 3]) = v;
        };

        f32x4 acc[4];
        #pragma unroll
        for (int mt = 0; mt < 4; mt++) acc[mt] = zero4();

        stageA(0, 0); stageB(0, 0);
        __syncthreads();
        for (int c = 0; c < 8; c++) {
            const int cb = c & 1;
            if (c + 1 < 8) { stageA(cb ^ 1, (c + 1) << 5); stageB(cb ^ 1, (c + 1) << 5); }
            f16x8 af[4], bf;
            bf = *(const f16x8*)(&Bb[cb][(((wc << 4) + nlo) << 5) + (q4 << 3)]);
            #pragma unroll
            for (int mt = 0; mt < 4; mt++)
                af[mt] = *(const f16x8*)(&Ab[cb][(((mt << 4) + nlo) << 5) + (q4 << 3)]);
            #pragma unroll
            for (int mt = 0; mt < 4; mt++)
                acc[mt] = MFMA16(af[mt], bf, acc[mt]);
            __syncthreads();
        }
        const int j = j0 + (wc << 4) + nlo;
        #pragma unroll
        for (int mt = 0; mt < 4; mt++) {
            const int cc = c0 + (mt << 4) + (q4 << 2);
            f16x4 pk;
            #pragma unroll
            for (int i = 0; i < 4; i++) pk[i] = (f16)acc[mt][i];
            *(f16x4*)(M2 + (((size_t)((b << 8) + j)) << 10) + cc) = pk;
        }
        return;
    }
    if (bid < 642) {
        int id = (bid - 512) * 256 + t;
        const float r = 1.99999f / 256.f;
        if (id < 32768) {
            float* dst = (id < 16384) ? cy : cx;
            int e = id & 16383;
            int row = e >> 7, f = e & 127;
            float s = -0.99999f + r + 2.f * r * (float)row;
            float coef = 6.283185307179586f * powf(10.f, (float)(f & 63) * (1.f / 64.f));
            float arg = coef * s;
            dst[e] = (f < 64) ? cosf(arg) : sinf(arg);
        } else {
            int id2 = id - 32768;           // 512 entries: frag-ordered last1_w
            int c = id2 >> 6, lane = id2 & 63;
            int nlo = lane & 15, q4 = lane >> 4;
            f16x8 v;
            #pragma unroll
            for (int ko = 0; ko < 8; ko++)
                v[ko] = (nlo < 3) ? (f16)(lw[nlo * 256 + (c << 5) + (q4 << 3) + ko] * SW_W) : (f16)0.f;
            *(f16x8*)(lwf + id2 * 8) = v;
        }
        return;
    }
    if (bid < 1186) {
        // conv_w (1028x1024 f32) -> cw16 (1088x1024 f16 *SW, zero-padded rows)
        const int g8 = (bid - 642) * 256 + t;
        const int row = g8 >> 7, col0 = (g8 & 127) << 3;
        f16x8 v;
        if (row < 1028) {
            const float* src = cw + (size_t)row * 1024 + col0;
            #pragma unroll
            for (int i = 0; i < 8; i++) v[i] = (f16)(src[i] * SW_W);
        } else {
            #pragma unroll
            for (int i = 0; i < 8; i++) v[i] = (f16)0.f;
        }
        *(f16x8*)(cw16 + (size_t)g8 * 8) = v;
        return;
    }
    {
        // S[j] = sum_k wfine[j,k]
        const float* src = wfine + (size_t)t * 256;
        float s = 0.f;
        for (int k = 0; k < 256; k += 4) {
            const f32x4 v = *(const f32x4*)(src + k);
            s += (v[0] + v[1]) + (v[2] + v[3]);
        }
        S[t] = s;
    }
}

// ---- GEMM-B: W[b][i][j] = (sum_c cw16[i,c]*M2T[b,j,c])/2^20 + conv_b[i]*S[j] + wfine_b[j] ----
__global__ __launch_bounds__(256, 4) void k_gemmB(
    const f16* __restrict__ cw16, const f16* __restrict__ M2,
    const float* __restrict__ conv_b, const float* __restrict__ S,
    const float* __restrict__ wfine_b, float* __restrict__ W)
{
    __shared__ __align__(16) f16 Ab[2][64 * 32];
    __shared__ __align__(16) f16 Bb[2][64 * 32];
    const int t = threadIdx.x;
    const int lane = t & 63;
    const int wc = t >> 6;
    const int nlo = lane & 15, q4 = lane >> 4;
    const int blk = blockIdx.x;                 // 544 = 8b * 17it * 4jt
    const int b = blk / 68, rem = blk % 68;
    const int it = rem >> 2, jt = rem & 3;
    const int i0 = it << 6, j0 = jt << 6;

    auto stageA = [&](int buf, int k0) {        // M2T rows (j)
        *(f16x8*)(&Ab[buf][t << 3]) =
            *(const f16x8*)(M2 + (((size_t)((b << 8) + j0 + (t >> 2))) << 10) + k0 + ((t & 3) << 3));
    };
    auto stageB = [&](int buf, int k0) {        // cw16 rows (i, padded)
        *(f16x8*)(&Bb[buf][t << 3]) =
            *(const f16x8*)(cw16 + (((size_t)(i0 + (t >> 2))) << 10) + k0 + ((t & 3) << 3));
    };

    f32x4 acc[4];
    #pragma unroll
    for (int mt = 0; mt < 4; mt++) acc[mt] = zero4();

    stageA(0, 0); stageB(0, 0);
    __syncthreads();
    for (int c = 0; c < 32; c++) {
        const int cb = c & 1;
        if (c + 1 < 32) { stageA(cb ^ 1, (c + 1) << 5); stageB(cb ^ 1, (c + 1) << 5); }
        f16x8 af[4], bf;
        bf = *(const f16x8*)(&Bb[cb][(((wc << 4) + nlo) << 5) + (q4 << 3)]);
        #pragma unroll
        for (int mt = 0; mt < 4; mt++)
            af[mt] = *(const f16x8*)(&Ab[cb][(((mt << 4) + nlo) << 5) + (q4 << 3)]);
        #pragma unroll
        for (int mt = 0; mt < 4; mt++)
            acc[mt] = MFMA16(af[mt], bf, acc[mt]);
        __syncthreads();
    }
    const int i = i0 + (wc << 4) + nlo;
    if (i < 1028) {
        const float cbv = conv_b[i];
        #pragma unroll
        for (int mt = 0; mt < 4; mt++) {
            const int j = j0 + (mt << 4) + (q4 << 2);
            const f32x4 sv = *(const f32x4*)(S + j);
            const f32x4 wb = *(const f32x4*)(wfine_b + j);
            f32x4 o;
            #pragma unroll
            for (int ii = 0; ii < 4; ii++)
                o[ii] = acc[mt][ii] * INV_SW2 + cbv * sv[ii] + wb[ii];
            *(f32x4*)(W + (((size_t)(b * 1028 + i)) << 8) + j) = o;
        }
    }
}

// ---- merged: axby (blocks 0..255) + castw fragment-order (blocks 256..639) ----
__global__ void k_wprep(const float* __restrict__ cy, const float* __restrict__ cx,
                        const float* __restrict__ W, f16* __restrict__ ayF,
                        f16* __restrict__ bxF, f16* __restrict__ wjT)
{
    __shared__ float tile[64][65];
    const int bid = blockIdx.x;
    const int t = threadIdx.x;
    if (bid < 256) {
        const int b = bid >> 5, which = (bid >> 4) & 1, rtile = bid & 15;
        const int r0 = rtile << 3;
        const float* ctab = which ? cx : cy;
        const float* Wb = W + (size_t)(b * 1028 + (which ? 128 : 0)) * 256;
        float acc[8];
        #pragma unroll
        for (int r = 0; r < 8; r++) acc[r] = 0.f;
        for (int k = 0; k < 128; k++) {
            const float wv = Wb[(k << 8) + t];
            #pragma unroll
            for (int r = 0; r < 8; r++)
                acc[r] = fmaf(ctab[((r0 + r) << 7) + k], wv, acc[r]);
        }
        const float b1v = which ? 0.f : W[(size_t)(b * 1028 + 256) * 256 + t];
        f16* dst = which ? bxF : ayF;
        for (int r = 0; r < 8; r++)
            dst[(size_t)((b << 7) + r0 + r) * 256 + t] = (f16)((acc[r] + b1v) * SA_A);
        return;
    }
    const int id = bid - 256;                  // 384 = 8b * 3jj * 16 tiles
    const int b = id / 48;
    const int rr = id % 48;
    const int jj = rr / 16;
    const int tt = rr % 16;
    const int kt = tt >> 2, wt = tt & 3;
    const int k0 = kt << 6, n0 = wt << 6;
    const float* src = W + (size_t)(b * 1028 + 257 * (jj + 1)) * 256;
    for (int i = 0; i < 16; i++) {
        int e = i * 256 + t;
        int kk = e >> 6, nn = e & 63;
        tile[kk][nn] = src[(size_t)(k0 + kk) * 256 + n0 + nn];
    }
    __syncthreads();
    f16* dst = wjT + (size_t)(b * 3 + jj) * 65536;
    #pragma unroll
    for (int i = 0; i < 2; i++) {
        const int g = i * 256 + t;
        const int c_rel = g >> 8, sub = g & 255;
        const int nt = sub >> 6, ln = sub & 63;
        const int nl = ln & 15, q4g = ln >> 4;
        f16x8 v;
        #pragma unroll
        for (int ko = 0; ko < 8; ko++)
            v[ko] = (f16)(tile[(c_rel << 5) + (q4g << 3) + ko][(nt << 4) + nl] * SW_W);
        const int c = (kt << 1) + c_rel;
        *(f16x8*)(dst + (size_t)(((((c << 2) | wt) << 2) | nt) << 9) + (ln << 3)) = v;
    }
}

// ---- fused MLP: layers 2..4 + final projection + silu ----
// R6 geometry (256 thr, 4 waves, wave owns 64px x 64n) + DEPTH-4 weight ring.
// launch_bounds(256,2) -> 256-reg/wave budget; ring ~196 regs, 60 headroom
// (R13's depth-3 spilled at the (256,3)=170 budget; this cell is spill-proof).
// Steady-state exposed latency L/3 ~ 233cy vs 156cy MFMA of 2 waves -> util up.
__global__ __launch_bounds__(256, 2) void k_main(
    const f16* __restrict__ wjT, const float* __restrict__ Wfull,
    const f16* __restrict__ ayF, const f16* __restrict__ bxF,
    const f16* __restrict__ lwf, const float* __restrict__ lb,
    const float* __restrict__ pa_p, float* __restrict__ out)
{
    __shared__ __align__(16) unsigned char actS[32768];     // 64px x 256f f16, slot-swizzled
    const int t = threadIdx.x;
    const int lane = t & 63;
    const int wc = t >> 6;
    const int nlo = lane & 15, q4 = lane >> 4;
    const int blk = blockIdx.x;
    const int b = blk & 7, rt = blk >> 3;      // batch = XCD index -> L2-local weights
    const int p0 = rt << 6;
    const int y = p0 >> 7, x0 = p0 & 127;
    const float pa = pa_p[0];

    const f16* wl0 = wjT + (size_t)(b * 3) * 65536;
    auto loadBg = [&](f16x8* dstv, int g) {
        const f16* p = wl0 + (size_t)(g >> 3) * 65536 + ((size_t)((((g & 7) << 2) | wc)) << 11) + (lane << 3);
        #pragma unroll
        for (int nt = 0; nt < 4; nt++) dstv[nt] = *(const f16x8*)(p + (nt << 9));
    };
    auto lbar = [&]() {      // LDS-drained barrier; vmem prefetch stays in flight
        asm volatile("s_waitcnt lgkmcnt(0)" ::: "memory");
        __builtin_amdgcn_s_barrier();
        __builtin_amdgcn_sched_barrier(0);
    };

    f16x8 bw[4][4];          // depth-4 weight ring: chunk g lives in bw[g%4]
    loadBg(bw[0], 0);
    loadBg(bw[1], 1);
    loadBg(bw[2], 2);

    // ---- init act = f16(prelu(ayF[y] + bxF[x])) ----
    {
        const int r = t & 63, g8 = t >> 6;
        const f16* ayr = ayF + (size_t)((b << 7) + y) * 256;
        const f16* bxr = bxF + (size_t)((b << 7) + x0 + r) * 256;
        const int rx = r & 7;
        #pragma unroll
        for (int mm = 0; mm < 8; mm++) {
            const int slot = (g8 << 3) + mm;
            const int f0 = slot << 3;
            f16x8 av = *(const f16x8*)(ayr + f0);
            f16x8 bv = *(const f16x8*)(bxr + f0);
            f16x8 v;
            #pragma unroll
            for (int i = 0; i < 8; i++) {
                float hv = (float)av[i] + (float)bv[i];
                hv = fmaxf(hv, 0.f) + pa * fminf(hv, 0.f);
                v[i] = (f16)hv;
            }
            *(f16x8*)(actS + (r << 9) + ((slot ^ rx) << 4)) = v;
        }
    }
    lbar();

    #pragma unroll
    for (int jj = 0; jj < 3; jj++) {
        const float* bias = Wfull + (size_t)(b * 1028 + 257 * (jj + 1) + 256) * 256;
        f32x4 bias4[4];
        #pragma unroll
        for (int nt = 0; nt < 4; nt++) {
            bias4[nt] = *(const f32x4*)(bias + (wc << 6) + (nt << 4) + (q4 << 2));
            bias4[nt] *= SA_A;
        }

        f32x4 acc[4][4];
        #pragma unroll
        for (int pt = 0; pt < 4; pt++)
            #pragma unroll
            for (int nt = 0; nt < 4; nt++) acc[pt][nt] = zero4();

        #pragma unroll
        for (int c = 0; c < 8; c++) {
            const int g = jj * 8 + c;               // compile-time after unroll
            if (g + 3 < 24) loadBg(bw[(g + 3) % 4], g + 3);   // prefetch 3 ahead
            const int sl = (c << 2) + q4;
            f16x8 af[4];
            #pragma unroll
            for (int pt = 0; pt < 4; pt++) {
                const int rr = (pt << 4) + nlo;
                af[pt] = *(const f16x8*)(actS + (rr << 9) + ((sl ^ (rr & 7)) << 4));
            }
            f16x8* curW = bw[g % 4];
            #pragma unroll
            for (int pt = 0; pt < 4; pt++)
                #pragma unroll
                for (int nt = 0; nt < 4; nt++)
                    acc[pt][nt] = MFMA16(curW[nt], af[pt], acc[pt][nt]);
        }
        lbar();   // all reads of actS done (LDS only; vmem prefetch survives)

        // epilogue: act <- f16(prelu(acc/SW + SA*b_j)); 8B packed writes
        #pragma unroll
        for (int nt = 0; nt < 4; nt++) {
            const int nb = (wc << 6) + (nt << 4) + (q4 << 2);
            #pragma unroll
            for (int pt = 0; pt < 4; pt++) {
                const int rr = (pt << 4) + nlo;
                f16x4 pk;
                #pragma unroll
                for (int i = 0; i < 4; i++) {
                    float v = fmaf(acc[pt][nt][i], INV_SW, bias4[nt][i]);
                    v = fmaxf(v, 0.f) + pa * fminf(v, 0.f);
                    pk[i] = (f16)v;
                }
                *(f16x4*)(actS + (rr << 9) + (((nb >> 3) ^ (rr & 7)) << 4) + ((nb & 7) << 1)) = pk;
            }
        }
        lbar();
    }

    // ---- final 256->3 projection + silu: each wave owns one 16-px tile ----
    {
        f32x4 acc2 = zero4();
        const int rr = (wc << 4) + nlo;
        #pragma unroll
        for (int c = 0; c < 8; c++) {
            const int sl = (c << 2) + q4;
            const f16x8 af = *(const f16x8*)(actS + (rr << 9) + ((sl ^ (rr & 7)) << 4));
            const f16x8 lf = *(const f16x8*)(lwf + (((c << 6) + lane) << 3));
            acc2 = MFMA16(af, lf, acc2);
        }
        if (nlo < 3) {
            const float lbv = lb[nlo];
            float* ob = out + ((size_t)(b * 3 + nlo) << 14) + p0 + (wc << 4) + (q4 << 2);
            #pragma unroll
            for (int i = 0; i < 4; i++) {
                float z = acc2[i] * INV_SASW + lbv;
                ob[i] = z / (1.f + expf(-z));
            }
        }
    }
}

extern "C" void kernel_launch(void* const* d_in, const int* in_sizes, int n_in,
                              void* d_out, int out_size, void* d_ws, size_t ws_size,
                              hipStream_t stream)
{
    (void)in_sizes; (void)n_in; (void)out_size; (void)ws_size;
    const float* x       = (const float*)d_in[0];
    const float* conv_w  = (const float*)d_in[1];
    const float* conv_b  = (const float*)d_in[2];
    const float* wfine_w = (const float*)d_in[3];
    const float* wfine_b = (const float*)d_in[4];
    const float* last1_w = (const float*)d_in[5];
    const float* last1_b = (const float*)d_in[6];
    const float* prelu_a = (const float*)d_in[7];
    char* ws = (char*)d_ws;
    float* Cy  = (float*)(ws + OFF_CY);
    float* Cx  = (float*)(ws + OFF_CX);
    f16*   lwf = (f16*)(ws + OFF_LW);
    float* S   = (float*)(ws + OFF_S);
    f16*   cw16= (f16*)(ws + OFF_CW);
    f16*   M2  = (f16*)(ws + OFF_M2);
    float* W   = (float*)(ws + OFF_W);
    f16*   AyF = (f16*)(ws + OFF_AY);
    f16*   BxF = (f16*)(ws + OFF_BX);
    f16*   wjT = (f16*)(ws + OFF_WT);

    k_prepA<<<1187, 256, 0, stream>>>(x, wfine_w, M2, Cy, Cx, lwf, last1_w, conv_w, cw16, S);
    k_gemmB<<<544, 256, 0, stream>>>(cw16, M2, conv_b, S, wfine_b, W);
    k_wprep<<<640, 256, 0, stream>>>(Cy, Cx, W, AyF, BxF, wjT);
    k_main<<<2048, 256, 0, stream>>>(wjT, W, AyF, BxF, lwf, last1_b, prelu_a, (float*)d_out);
}

// Round 20
// 112.786 us; speedup vs baseline: 1.1619x; 1.0169x over previous
//
#include <hip/hip_runtime.h>
#include <hip/hip_fp16.h>
#include <math.h>

typedef _Float16 f16;
typedef _Float16 f16x2 __attribute__((ext_vector_type(2)));
typedef __fp16 h16x2 __attribute__((ext_vector_type(2)));
typedef _Float16 f16x4 __attribute__((ext_vector_type(4)));
typedef _Float16 f16x8 __attribute__((ext_vector_type(8)));
typedef float f32x4 __attribute__((ext_vector_type(4)));

#define MFMA16(a, b, c) __builtin_amdgcn_mfma_f32_16x16x32_f16((a), (b), (c), 0, 0, 0)

static __device__ inline f16x2 pkrtz(float a, float b) {
    h16x2 h = __builtin_amdgcn_cvt_pkrtz(a, b);
    union { h16x2 h; f16x2 f; } u;
    u.h = h;
    return u.f;
}

static constexpr float SW_W    = 1024.f;              // weight scale (exact pow2)
static constexpr float SA_A    = 64.f;                // main-loop activation scale
static constexpr float INV_SW  = 1.f / 1024.f;
static constexpr float INV_SW2 = 1.f / (1024.f * 1024.f);
static constexpr float INV_SASW = 1.f / (64.f * 1024.f);

// workspace layout (bytes)
static constexpr size_t OFF_CY = 0;                         // 128*128 f32
static constexpr size_t OFF_CX = OFF_CY + 65536;
static constexpr size_t OFF_LW = OFF_CX + 65536;            // 512*8 f16 frag-ordered last1_w*SW
static constexpr size_t OFF_S  = OFF_LW + 8192;             // 256 f32 rowsum(wfine)
static constexpr size_t OFF_CW = OFF_S  + 1024;             // 1088*1024 f16 conv_w*SW (padded)
static constexpr size_t OFF_M2 = OFF_CW + (size_t)1088 * 1024 * 2;  // 8*256*1024 f16  M2T[b][j][c]
static constexpr size_t OFF_W  = OFF_M2 + (size_t)8 * 256 * 1024 * 2; // 8*1028*256 f32
static constexpr size_t OFF_AY = OFF_W  + (size_t)8 * 1028 * 256 * 4; // 8*128*256 f16
static constexpr size_t OFF_BX = OFF_AY + (size_t)8 * 128 * 256 * 2;  // 8*128*256 f16
static constexpr size_t OFF_WT = OFF_BX + (size_t)8 * 128 * 256 * 2;  // 8*3*65536 f16 frag wj*SW

static __device__ inline f32x4 zero4() { f32x4 v = {0.f, 0.f, 0.f, 0.f}; return v; }

// ---- K1: gemmA (blocks 0..511) | PE tables + lwf (512..641) | conv_w cast (642..1185) | S (1186) ----
__global__ __launch_bounds__(256, 4) void k_prepA(
    const float* __restrict__ x, const float* __restrict__ wfine,
    f16* __restrict__ M2,
    float* __restrict__ cy, float* __restrict__ cx,
    f16* __restrict__ lwf, const float* __restrict__ lw,
    const float* __restrict__ cw, f16* __restrict__ cw16,
    float* __restrict__ S)
{
    __shared__ __align__(16) f16 Ab[2][64 * 32];
    __shared__ __align__(16) f16 Bb[2][64 * 32];
    const int bid = blockIdx.x;
    const int t = threadIdx.x;
    if (bid < 512) {
        const int lane = t & 63;
        const int wc = t >> 6;
        const int nlo = lane & 15, q4 = lane >> 4;
        const int b = bid >> 6, rem = bid & 63;
        const int jt = rem >> 4, ct = rem & 15;
        const int j0 = jt << 6, c0 = ct << 6;

        auto stageA = [&](int buf, int k0) {        // x rows (c) -> f16
            const float* src = x + (((size_t)((b << 10) + c0 + (t >> 2))) << 8) + k0 + ((t & 3) << 3);
            f16x8 v;
            #pragma unroll
            for (int i = 0; i < 8; i++) v[i] = (f16)src[i];
            *(f16x8*)(&Ab[buf][t << 3]) = v;
        };
        auto stageB = [&](int buf, int k0) {        // wfine rows (j) -> f16 *SW
            const float* src = wfine + (size_t)(j0 + (t >> 2)) * 256 + k0 + ((t & 3) << 3);
            f16x8 v;
            #pragma unroll
            for (int i = 0; i < 8; i++) v[i] = (f16)(src[i] * SW_W);
            *(f16x8*)(&Bb[buf][t << 3]) = v;
        };

        f32x4 acc[4];
        #pragma unroll
        for (int mt = 0; mt < 4; mt++) acc[mt] = zero4();

        stageA(0, 0); stageB(0, 0);
        __syncthreads();
        for (int c = 0; c < 8; c++) {
            const int cb = c & 1;
            if (c + 1 < 8) { stageA(cb ^ 1, (c + 1) << 5); stageB(cb ^ 1, (c + 1) << 5); }
            f16x8 af[4], bf;
            bf = *(const f16x8*)(&Bb[cb][(((wc << 4) + nlo) << 5) + (q4 << 3)]);
            #pragma unroll
            for (int mt = 0; mt < 4; mt++)
                af[mt] = *(const f16x8*)(&Ab[cb][(((mt << 4) + nlo) << 5) + (q4 << 3)]);
            #pragma unroll
            for (int mt = 0; mt < 4; mt++)
                acc[mt] = MFMA16(af[mt], bf, acc[mt]);
            __syncthreads();
        }
        const int j = j0 + (wc << 4) + nlo;
        #pragma unroll
        for (int mt = 0; mt < 4; mt++) {
            const int cc = c0 + (mt << 4) + (q4 << 2);
            f16x4 pk;
            #pragma unroll
            for (int i = 0; i < 4; i++) pk[i] = (f16)acc[mt][i];
            *(f16x4*)(M2 + (((size_t)((b << 8) + j)) << 10) + cc) = pk;
        }
        return;
    }
    if (bid < 642) {
        int id = (bid - 512) * 256 + t;
        const float r = 1.99999f / 256.f;
        if (id < 32768) {
            float* dst = (id < 16384) ? cy : cx;
            int e = id & 16383;
            int row = e >> 7, f = e & 127;
            float s = -0.99999f + r + 2.f * r * (float)row;
            float coef = 6.283185307179586f * powf(10.f, (float)(f & 63) * (1.f / 64.f));
            float arg = coef * s;
            dst[e] = (f < 64) ? cosf(arg) : sinf(arg);
        } else {
            int id2 = id - 32768;           // 512 entries: frag-ordered last1_w
            int c = id2 >> 6, lane = id2 & 63;
            int nlo = lane & 15, q4 = lane >> 4;
            f16x8 v;
            #pragma unroll
            for (int ko = 0; ko < 8; ko++)
                v[ko] = (nlo < 3) ? (f16)(lw[nlo * 256 + (c << 5) + (q4 << 3) + ko] * SW_W) : (f16)0.f;
            *(f16x8*)(lwf + id2 * 8) = v;
        }
        return;
    }
    if (bid < 1186) {
        // conv_w (1028x1024 f32) -> cw16 (1088x1024 f16 *SW, zero-padded rows)
        const int g8 = (bid - 642) * 256 + t;
        const int row = g8 >> 7, col0 = (g8 & 127) << 3;
        f16x8 v;
        if (row < 1028) {
            const float* src = cw + (size_t)row * 1024 + col0;
            #pragma unroll
            for (int i = 0; i < 8; i++) v[i] = (f16)(src[i] * SW_W);
        } else {
            #pragma unroll
            for (int i = 0; i < 8; i++) v[i] = (f16)0.f;
        }
        *(f16x8*)(cw16 + (size_t)g8 * 8) = v;
        return;
    }
    {
        // S[j] = sum_k wfine[j,k]
        const float* src = wfine + (size_t)t * 256;
        float s = 0.f;
        for (int k = 0; k < 256; k += 4) {
            const f32x4 v = *(const f32x4*)(src + k);
            s += (v[0] + v[1]) + (v[2] + v[3]);
        }
        S[t] = s;
    }
}

// ---- GEMM-B: W[b][i][j] = (sum_c cw16[i,c]*M2T[b,j,c])/2^20 + conv_b[i]*S[j] + wfine_b[j] ----
__global__ __launch_bounds__(256, 4) void k_gemmB(
    const f16* __restrict__ cw16, const f16* __restrict__ M2,
    const float* __restrict__ conv_b, const float* __restrict__ S,
    const float* __restrict__ wfine_b, float* __restrict__ W)
{
    __shared__ __align__(16) f16 Ab[2][64 * 32];
    __shared__ __align__(16) f16 Bb[2][64 * 32];
    const int t = threadIdx.x;
    const int lane = t & 63;
    const int wc = t >> 6;
    const int nlo = lane & 15, q4 = lane >> 4;
    const int blk = blockIdx.x;                 // 544 = 8b * 17it * 4jt
    const int b = blk / 68, rem = blk % 68;
    const int it = rem >> 2, jt = rem & 3;
    const int i0 = it << 6, j0 = jt << 6;

    auto stageA = [&](int buf, int k0) {        // M2T rows (j)
        *(f16x8*)(&Ab[buf][t << 3]) =
            *(const f16x8*)(M2 + (((size_t)((b << 8) + j0 + (t >> 2))) << 10) + k0 + ((t & 3) << 3));
    };
    auto stageB = [&](int buf, int k0) {        // cw16 rows (i, padded)
        *(f16x8*)(&Bb[buf][t << 3]) =
            *(const f16x8*)(cw16 + (((size_t)(i0 + (t >> 2))) << 10) + k0 + ((t & 3) << 3));
    };

    f32x4 acc[4];
    #pragma unroll
    for (int mt = 0; mt < 4; mt++) acc[mt] = zero4();

    stageA(0, 0); stageB(0, 0);
    __syncthreads();
    for (int c = 0; c < 32; c++) {
        const int cb = c & 1;
        if (c + 1 < 32) { stageA(cb ^ 1, (c + 1) << 5); stageB(cb ^ 1, (c + 1) << 5); }
        f16x8 af[4], bf;
        bf = *(const f16x8*)(&Bb[cb][(((wc << 4) + nlo) << 5) + (q4 << 3)]);
        #pragma unroll
        for (int mt = 0; mt < 4; mt++)
            af[mt] = *(const f16x8*)(&Ab[cb][(((mt << 4) + nlo) << 5) + (q4 << 3)]);
        #pragma unroll
        for (int mt = 0; mt < 4; mt++)
            acc[mt] = MFMA16(af[mt], bf, acc[mt]);
        __syncthreads();
    }
    const int i = i0 + (wc << 4) + nlo;
    if (i < 1028) {
        const float cbv = conv_b[i];
        #pragma unroll
        for (int mt = 0; mt < 4; mt++) {
            const int j = j0 + (mt << 4) + (q4 << 2);
            const f32x4 sv = *(const f32x4*)(S + j);
            const f32x4 wb = *(const f32x4*)(wfine_b + j);
            f32x4 o;
            #pragma unroll
            for (int ii = 0; ii < 4; ii++)
                o[ii] = acc[mt][ii] * INV_SW2 + cbv * sv[ii] + wb[ii];
            *(f32x4*)(W + (((size_t)(b * 1028 + i)) << 8) + j) = o;
        }
    }
}

// ---- merged: axby (blocks 0..255) + castw fragment-order (blocks 256..639) ----
__global__ void k_wprep(const float* __restrict__ cy, const float* __restrict__ cx,
                        const float* __restrict__ W, f16* __restrict__ ayF,
                        f16* __restrict__ bxF, f16* __restrict__ wjT)
{
    __shared__ float tile[64][65];
    const int bid = blockIdx.x;
    const int t = threadIdx.x;
    if (bid < 256) {
        const int b = bid >> 5, which = (bid >> 4) & 1, rtile = bid & 15;
        const int r0 = rtile << 3;
        const float* ctab = which ? cx : cy;
        const float* Wb = W + (size_t)(b * 1028 + (which ? 128 : 0)) * 256;
        float acc[8];
        #pragma unroll
        for (int r = 0; r < 8; r++) acc[r] = 0.f;
        for (int k = 0; k < 128; k++) {
            const float wv = Wb[(k << 8) + t];
            #pragma unroll
            for (int r = 0; r < 8; r++)
                acc[r] = fmaf(ctab[((r0 + r) << 7) + k], wv, acc[r]);
        }
        const float b1v = which ? 0.f : W[(size_t)(b * 1028 + 256) * 256 + t];
        f16* dst = which ? bxF : ayF;
        for (int r = 0; r < 8; r++)
            dst[(size_t)((b << 7) + r0 + r) * 256 + t] = (f16)((acc[r] + b1v) * SA_A);
        return;
    }
    const int id = bid - 256;                  // 384 = 8b * 3jj * 16 tiles
    const int b = id / 48;
    const int rr = id % 48;
    const int jj = rr / 16;
    const int tt = rr % 16;
    const int kt = tt >> 2, wt = tt & 3;
    const int k0 = kt << 6, n0 = wt << 6;
    const float* src = W + (size_t)(b * 1028 + 257 * (jj + 1)) * 256;
    for (int i = 0; i < 16; i++) {
        int e = i * 256 + t;
        int kk = e >> 6, nn = e & 63;
        tile[kk][nn] = src[(size_t)(k0 + kk) * 256 + n0 + nn];
    }
    __syncthreads();
    f16* dst = wjT + (size_t)(b * 3 + jj) * 65536;
    #pragma unroll
    for (int i = 0; i < 2; i++) {
        const int g = i * 256 + t;
        const int c_rel = g >> 8, sub = g & 255;
        const int nt = sub >> 6, ln = sub & 63;
        const int nl = ln & 15, q4g = ln >> 4;
        f16x8 v;
        #pragma unroll
        for (int ko = 0; ko < 8; ko++)
            v[ko] = (f16)(tile[(c_rel << 5) + (q4g << 3) + ko][(nt << 4) + nl] * SW_W);
        const int c = (kt << 1) + c_rel;
        *(f16x8*)(dst + (size_t)(((((c << 2) | wt) << 2) | nt) << 9) + (ln << 3)) = v;
    }
}

// ---- fused MLP: layers 2..4 + final projection + silu ----
// R14 structure (best measured: 256 thr, depth-2 persistent weight dbuf, lbar)
// with packed f32->f16 conversion (v_cvt_pkrtz) in init + epilogue to cut the
// co-dominant VALU term (VALUBusy 31-37% > MfmaUtil 30%).
__global__ __launch_bounds__(256, 3) void k_main(
    const f16* __restrict__ wjT, const float* __restrict__ Wfull,
    const f16* __restrict__ ayF, const f16* __restrict__ bxF,
    const f16* __restrict__ lwf, const float* __restrict__ lb,
    const float* __restrict__ pa_p, float* __restrict__ out)
{
    __shared__ __align__(16) unsigned char actS[32768];     // 64px x 256f f16, slot-swizzled
    const int t = threadIdx.x;
    const int lane = t & 63;
    const int wc = t >> 6;
    const int nlo = lane & 15, q4 = lane >> 4;
    const int blk = blockIdx.x;
    const int b = blk & 7, rt = blk >> 3;      // batch = XCD index -> L2-local weights
    const int p0 = rt << 6;
    const int y = p0 >> 7, x0 = p0 & 127;
    const float pa = pa_p[0];

    const f16* wl0 = wjT + (size_t)(b * 3) * 65536;
    auto loadBg = [&](f16x8* dstv, int g) {
        const f16* p = wl0 + (size_t)(g >> 3) * 65536 + ((size_t)((((g & 7) << 2) | wc)) << 11) + (lane << 3);
        #pragma unroll
        for (int nt = 0; nt < 4; nt++) dstv[nt] = *(const f16x8*)(p + (nt << 9));
    };
    auto lbar = [&]() {      // LDS-drained barrier; vmem prefetch stays in flight
        asm volatile("s_waitcnt lgkmcnt(0)" ::: "memory");
        __builtin_amdgcn_s_barrier();
        __builtin_amdgcn_sched_barrier(0);
    };
    auto prelu4pk = [&](const f32x4 a, const f32x4 bsc) -> f16x4 {
        float v0 = fmaf(a[0], INV_SW, bsc[0]);
        float v1 = fmaf(a[1], INV_SW, bsc[1]);
        float v2 = fmaf(a[2], INV_SW, bsc[2]);
        float v3 = fmaf(a[3], INV_SW, bsc[3]);
        v0 = fmaxf(v0, 0.f) + pa * fminf(v0, 0.f);
        v1 = fmaxf(v1, 0.f) + pa * fminf(v1, 0.f);
        v2 = fmaxf(v2, 0.f) + pa * fminf(v2, 0.f);
        v3 = fmaxf(v3, 0.f) + pa * fminf(v3, 0.f);
        f16x2 lo = pkrtz(v0, v1);
        f16x2 hi = pkrtz(v2, v3);
        f16x4 r;
        r[0] = lo[0]; r[1] = lo[1]; r[2] = hi[0]; r[3] = hi[1];
        return r;
    };

    f16x8 bfA[4], bfB[4];
    loadBg(bfA, 0);          // persistent cross-layer weight double-buffer

    // ---- init act = f16(prelu(ayF[y] + bxF[x])), packed cvt ----
    {
        const int r = t & 63, g8 = t >> 6;
        const f16* ayr = ayF + (size_t)((b << 7) + y) * 256;
        const f16* bxr = bxF + (size_t)((b << 7) + x0 + r) * 256;
        const int rx = r & 7;
        #pragma unroll
        for (int mm = 0; mm < 8; mm++) {
            const int slot = (g8 << 3) + mm;
            const int f0 = slot << 3;
            f16x8 av = *(const f16x8*)(ayr + f0);
            f16x8 bv = *(const f16x8*)(bxr + f0);
            f16x8 v;
            #pragma unroll
            for (int i2 = 0; i2 < 4; i2++) {
                float h0 = (float)av[2 * i2] + (float)bv[2 * i2];
                float h1 = (float)av[2 * i2 + 1] + (float)bv[2 * i2 + 1];
                h0 = fmaxf(h0, 0.f) + pa * fminf(h0, 0.f);
                h1 = fmaxf(h1, 0.f) + pa * fminf(h1, 0.f);
                f16x2 pk2 = pkrtz(h0, h1);
                v[2 * i2] = pk2[0]; v[2 * i2 + 1] = pk2[1];
            }
            *(f16x8*)(actS + (r << 9) + ((slot ^ rx) << 4)) = v;
        }
    }
    lbar();

    for (int jj = 0; jj < 3; jj++) {
        const float* bias = Wfull + (size_t)(b * 1028 + 257 * (jj + 1) + 256) * 256;
        f32x4 bias4[4];
        #pragma unroll
        for (int nt = 0; nt < 4; nt++) {
            bias4[nt] = *(const f32x4*)(bias + (wc << 6) + (nt << 4) + (q4 << 2));
            bias4[nt] *= SA_A;
        }

        f32x4 acc[4][4];
        #pragma unroll
        for (int pt = 0; pt < 4; pt++)
            #pragma unroll
            for (int nt = 0; nt < 4; nt++) acc[pt][nt] = zero4();

        #pragma unroll
        for (int c = 0; c < 8; c++) {
            const int g = jj * 8 + c;
            f16x8* curW = (c & 1) ? bfB : bfA;     // g&1 == c&1 (jj*8 even)
            f16x8* nxtW = (c & 1) ? bfA : bfB;
            if (g < 23) loadBg(nxtW, g + 1);       // crosses layer boundary at c==7
            const int sl = (c << 2) + q4;
            f16x8 af[4];
            #pragma unroll
            for (int pt = 0; pt < 4; pt++) {
                const int rr = (pt << 4) + nlo;
                af[pt] = *(const f16x8*)(actS + (rr << 9) + ((sl ^ (rr & 7)) << 4));
            }
            #pragma unroll
            for (int pt = 0; pt < 4; pt++)
                #pragma unroll
                for (int nt = 0; nt < 4; nt++)
                    acc[pt][nt] = MFMA16(curW[nt], af[pt], acc[pt][nt]);
        }
        lbar();   // all reads of actS done (LDS only; vmem prefetch survives)

        // epilogue: act <- f16(prelu(acc/SW + SA*b_j)); packed cvt, 8B writes
        #pragma unroll
        for (int nt = 0; nt < 4; nt++) {
            const int nb = (wc << 6) + (nt << 4) + (q4 << 2);
            #pragma unroll
            for (int pt = 0; pt < 4; pt++) {
                const int rr = (pt << 4) + nlo;
                f16x4 pk = prelu4pk(acc[pt][nt], bias4[nt]);
                *(f16x4*)(actS + (rr << 9) + (((nb >> 3) ^ (rr & 7)) << 4) + ((nb & 7) << 1)) = pk;
            }
        }
        lbar();
    }

    // ---- final 256->3 projection + silu: each wave owns one 16-px tile ----
    {
        f32x4 acc2 = zero4();
        const int rr = (wc << 4) + nlo;
        #pragma unroll
        for (int c = 0; c < 8; c++) {
            const int sl = (c << 2) + q4;
            const f16x8 af = *(const f16x8*)(actS + (rr << 9) + ((sl ^ (rr & 7)) << 4));
            const f16x8 lf = *(const f16x8*)(lwf + (((c << 6) + lane) << 3));
            acc2 = MFMA16(af, lf, acc2);
        }
        if (nlo < 3) {
            const float lbv = lb[nlo];
            float* ob = out + ((size_t)(b * 3 + nlo) << 14) + p0 + (wc << 4) + (q4 << 2);
            #pragma unroll
            for (int i = 0; i < 4; i++) {
                float z = acc2[i] * INV_SASW + lbv;
                ob[i] = z / (1.f + expf(-z));
            }
        }
    }
}

extern "C" void kernel_launch(void* const* d_in, const int* in_sizes, int n_in,
                              void* d_out, int out_size, void* d_ws, size_t ws_size,
                              hipStream_t stream)
{
    (void)in_sizes; (void)n_in; (void)out_size; (void)ws_size;
    const float* x       = (const float*)d_in[0];
    const float* conv_w  = (const float*)d_in[1];
    const float* conv_b  = (const float*)d_in[2];
    const float* wfine_w = (const float*)d_in[3];
    const float* wfine_b = (const float*)d_in[4];
    const float* last1_w = (const float*)d_in[5];
    const float* last1_b = (const float*)d_in[6];
    const float* prelu_a = (const float*)d_in[7];
    char* ws = (char*)d_ws;
    float* Cy  = (float*)(ws + OFF_CY);
    float* Cx  = (float*)(ws + OFF_CX);
    f16*   lwf = (f16*)(ws + OFF_LW);
    float* S   = (float*)(ws + OFF_S);
    f16*   cw16= (f16*)(ws + OFF_CW);
    f16*   M2  = (f16*)(ws + OFF_M2);
    float* W   = (float*)(ws + OFF_W);
    f16*   AyF = (f16*)(ws + OFF_AY);
    f16*   BxF = (f16*)(ws + OFF_BX);
    f16*   wjT = (f16*)(ws + OFF_WT);

    k_prepA<<<1187, 256, 0, stream>>>(x, wfine_w, M2, Cy, Cx, lwf, last1_w, conv_w, cw16, S);
    k_gemmB<<<544, 256, 0, stream>>>(cw16, M2, conv_b, S, wfine_b, W);
    k_wprep<<<640, 256, 0, stream>>>(Cy, Cx, W, AyF, BxF, wjT);
    k_main<<<2048, 256, 0, stream>>>(wjT, W, AyF, BxF, lwf, last1_b, prelu_a, (float*)d_out);
}

// Round 21
// 112.386 us; speedup vs baseline: 1.1660x; 1.0036x over previous
//
#include <hip/hip_runtime.h>
#include <hip/hip_fp16.h>
#include <math.h>

typedef _Float16 f16;
typedef _Float16 f16x2 __attribute__((ext_vector_type(2)));
typedef __fp16 h16x2 __attribute__((ext_vector_type(2)));
typedef _Float16 f16x4 __attribute__((ext_vector_type(4)));
typedef _Float16 f16x8 __attribute__((ext_vector_type(8)));
typedef float f32x4 __attribute__((ext_vector_type(4)));

#define MFMA16(a, b, c) __builtin_amdgcn_mfma_f32_16x16x32_f16((a), (b), (c), 0, 0, 0)

static __device__ inline f16x2 pkrtz(float a, float b) {
    h16x2 h = __builtin_amdgcn_cvt_pkrtz(a, b);
    union { h16x2 h; f16x2 f; } u;
    u.h = h;
    return u.f;
}

static constexpr float SW_W    = 1024.f;              // weight scale (exact pow2)
static constexpr float SA_A    = 64.f;                // main-loop activation scale
static constexpr float INV_SW  = 1.f / 1024.f;
static constexpr float INV_SW2 = 1.f / (1024.f * 1024.f);
static constexpr float INV_SASW = 1.f / (64.f * 1024.f);

// workspace layout (bytes)
static constexpr size_t OFF_CY = 0;                         // 128*128 f32
static constexpr size_t OFF_CX = OFF_CY + 65536;
static constexpr size_t OFF_LW = OFF_CX + 65536;            // 512*8 f16 frag-ordered last1_w*SW
static constexpr size_t OFF_S  = OFF_LW + 8192;             // 256 f32 rowsum(wfine)
static constexpr size_t OFF_CW = OFF_S  + 1024;             // 1088*1024 f16 conv_w*SW (padded)
static constexpr size_t OFF_M2 = OFF_CW + (size_t)1088 * 1024 * 2;  // 8*256*1024 f16  M2T[b][j][c]
static constexpr size_t OFF_W  = OFF_M2 + (size_t)8 * 256 * 1024 * 2; // 8*1028*256 f32
static constexpr size_t OFF_AY = OFF_W  + (size_t)8 * 1028 * 256 * 4; // 8*128*256 f16
static constexpr size_t OFF_BX = OFF_AY + (size_t)8 * 128 * 256 * 2;  // 8*128*256 f16
static constexpr size_t OFF_WT = OFF_BX + (size_t)8 * 128 * 256 * 2;  // 8*3*65536 f16 frag wj*SW

static __device__ inline f32x4 zero4() { f32x4 v = {0.f, 0.f, 0.f, 0.f}; return v; }

// ---- K1: gemmA (blocks 0..511) | PE tables + lwf (512..641) | conv_w cast (642..1185) | S (1186) ----
__global__ __launch_bounds__(256, 4) void k_prepA(
    const float* __restrict__ x, const float* __restrict__ wfine,
    f16* __restrict__ M2,
    float* __restrict__ cy, float* __restrict__ cx,
    f16* __restrict__ lwf, const float* __restrict__ lw,
    const float* __restrict__ cw, f16* __restrict__ cw16,
    float* __restrict__ S)
{
    __shared__ __align__(16) f16 Ab[2][64 * 32];
    __shared__ __align__(16) f16 Bb[2][64 * 32];
    const int bid = blockIdx.x;
    const int t = threadIdx.x;
    if (bid < 512) {
        const int lane = t & 63;
        const int wc = t >> 6;
        const int nlo = lane & 15, q4 = lane >> 4;
        const int b = bid >> 6, rem = bid & 63;
        const int jt = rem >> 4, ct = rem & 15;
        const int j0 = jt << 6, c0 = ct << 6;

        auto stageA = [&](int buf, int k0) {        // x rows (c) -> f16
            const float* src = x + (((size_t)((b << 10) + c0 + (t >> 2))) << 8) + k0 + ((t & 3) << 3);
            f16x8 v;
            #pragma unroll
            for (int i = 0; i < 8; i++) v[i] = (f16)src[i];
            *(f16x8*)(&Ab[buf][t << 3]) = v;
        };
        auto stageB = [&](int buf, int k0) {        // wfine rows (j) -> f16 *SW
            const float* src = wfine + (size_t)(j0 + (t >> 2)) * 256 + k0 + ((t & 3) << 3);
            f16x8 v;
            #pragma unroll
            for (int i = 0; i < 8; i++) v[i] = (f16)(src[i] * SW_W);
            *(f16x8*)(&Bb[buf][t << 3]) = v;
        };

        f32x4 acc[4];
        #pragma unroll
        for (int mt = 0; mt < 4; mt++) acc[mt] = zero4();

        stageA(0, 0); stageB(0, 0);
        __syncthreads();
        for (int c = 0; c < 8; c++) {
            const int cb = c & 1;
            if (c + 1 < 8) { stageA(cb ^ 1, (c + 1) << 5); stageB(cb ^ 1, (c + 1) << 5); }
            f16x8 af[4], bf;
            bf = *(const f16x8*)(&Bb[cb][(((wc << 4) + nlo) << 5) + (q4 << 3)]);
            #pragma unroll
            for (int mt = 0; mt < 4; mt++)
                af[mt] = *(const f16x8*)(&Ab[cb][(((mt << 4) + nlo) << 5) + (q4 << 3)]);
            #pragma unroll
            for (int mt = 0; mt < 4; mt++)
                acc[mt] = MFMA16(af[mt], bf, acc[mt]);
            __syncthreads();
        }
        const int j = j0 + (wc << 4) + nlo;
        #pragma unroll
        for (int mt = 0; mt < 4; mt++) {
            const int cc = c0 + (mt << 4) + (q4 << 2);
            f16x4 pk;
            #pragma unroll
            for (int i = 0; i < 4; i++) pk[i] = (f16)acc[mt][i];
            *(f16x4*)(M2 + (((size_t)((b << 8) + j)) << 10) + cc) = pk;
        }
        return;
    }
    if (bid < 642) {
        int id = (bid - 512) * 256 + t;
        const float r = 1.99999f / 256.f;
        if (id < 32768) {
            float* dst = (id < 16384) ? cy : cx;
            int e = id & 16383;
            int row = e >> 7, f = e & 127;
            float s = -0.99999f + r + 2.f * r * (float)row;
            float coef = 6.283185307179586f * powf(10.f, (float)(f & 63) * (1.f / 64.f));
            float arg = coef * s;
            dst[e] = (f < 64) ? cosf(arg) : sinf(arg);
        } else {
            int id2 = id - 32768;           // 512 entries: frag-ordered last1_w
            int c = id2 >> 6, lane = id2 & 63;
            int nlo = lane & 15, q4 = lane >> 4;
            f16x8 v;
            #pragma unroll
            for (int ko = 0; ko < 8; ko++)
                v[ko] = (nlo < 3) ? (f16)(lw[nlo * 256 + (c << 5) + (q4 << 3) + ko] * SW_W) : (f16)0.f;
            *(f16x8*)(lwf + id2 * 8) = v;
        }
        return;
    }
    if (bid < 1186) {
        // conv_w (1028x1024 f32) -> cw16 (1088x1024 f16 *SW, zero-padded rows)
        const int g8 = (bid - 642) * 256 + t;
        const int row = g8 >> 7, col0 = (g8 & 127) << 3;
        f16x8 v;
        if (row < 1028) {
            const float* src = cw + (size_t)row * 1024 + col0;
            #pragma unroll
            for (int i = 0; i < 8; i++) v[i] = (f16)(src[i] * SW_W);
        } else {
            #pragma unroll
            for (int i = 0; i < 8; i++) v[i] = (f16)0.f;
        }
        *(f16x8*)(cw16 + (size_t)g8 * 8) = v;
        return;
    }
    {
        // S[j] = sum_k wfine[j,k]
        const float* src = wfine + (size_t)t * 256;
        float s = 0.f;
        for (int k = 0; k < 256; k += 4) {
            const f32x4 v = *(const f32x4*)(src + k);
            s += (v[0] + v[1]) + (v[2] + v[3]);
        }
        S[t] = s;
    }
}

// ---- GEMM-B: W[b][i][j] = (sum_c cw16[i,c]*M2T[b,j,c])/2^20 + conv_b[i]*S[j] + wfine_b[j] ----
__global__ __launch_bounds__(256, 4) void k_gemmB(
    const f16* __restrict__ cw16, const f16* __restrict__ M2,
    const float* __restrict__ conv_b, const float* __restrict__ S,
    const float* __restrict__ wfine_b, float* __restrict__ W)
{
    __shared__ __align__(16) f16 Ab[2][64 * 32];
    __shared__ __align__(16) f16 Bb[2][64 * 32];
    const int t = threadIdx.x;
    const int lane = t & 63;
    const int wc = t >> 6;
    const int nlo = lane & 15, q4 = lane >> 4;
    const int blk = blockIdx.x;                 // 544 = 8b * 17it * 4jt
    const int b = blk / 68, rem = blk % 68;
    const int it = rem >> 2, jt = rem & 3;
    const int i0 = it << 6, j0 = jt << 6;

    auto stageA = [&](int buf, int k0) {        // M2T rows (j)
        *(f16x8*)(&Ab[buf][t << 3]) =
            *(const f16x8*)(M2 + (((size_t)((b << 8) + j0 + (t >> 2))) << 10) + k0 + ((t & 3) << 3));
    };
    auto stageB = [&](int buf, int k0) {        // cw16 rows (i, padded)
        *(f16x8*)(&Bb[buf][t << 3]) =
            *(const f16x8*)(cw16 + (((size_t)(i0 + (t >> 2))) << 10) + k0 + ((t & 3) << 3));
    };

    f32x4 acc[4];
    #pragma unroll
    for (int mt = 0; mt < 4; mt++) acc[mt] = zero4();

    stageA(0, 0); stageB(0, 0);
    __syncthreads();
    for (int c = 0; c < 32; c++) {
        const int cb = c & 1;
        if (c + 1 < 32) { stageA(cb ^ 1, (c + 1) << 5); stageB(cb ^ 1, (c + 1) << 5); }
        f16x8 af[4], bf;
        bf = *(const f16x8*)(&Bb[cb][(((wc << 4) + nlo) << 5) + (q4 << 3)]);
        #pragma unroll
        for (int mt = 0; mt < 4; mt++)
            af[mt] = *(const f16x8*)(&Ab[cb][(((mt << 4) + nlo) << 5) + (q4 << 3)]);
        #pragma unroll
        for (int mt = 0; mt < 4; mt++)
            acc[mt] = MFMA16(af[mt], bf, acc[mt]);
        __syncthreads();
    }
    const int i = i0 + (wc << 4) + nlo;
    if (i < 1028) {
        const float cbv = conv_b[i];
        #pragma unroll
        for (int mt = 0; mt < 4; mt++) {
            const int j = j0 + (mt << 4) + (q4 << 2);
            const f32x4 sv = *(const f32x4*)(S + j);
            const f32x4 wb = *(const f32x4*)(wfine_b + j);
            f32x4 o;
            #pragma unroll
            for (int ii = 0; ii < 4; ii++)
                o[ii] = acc[mt][ii] * INV_SW2 + cbv * sv[ii] + wb[ii];
            *(f32x4*)(W + (((size_t)(b * 1028 + i)) << 8) + j) = o;
        }
    }
}

// ---- merged: axby (blocks 0..255) + castw fragment-order (blocks 256..639) ----
__global__ void k_wprep(const float* __restrict__ cy, const float* __restrict__ cx,
                        const float* __restrict__ W, f16* __restrict__ ayF,
                        f16* __restrict__ bxF, f16* __restrict__ wjT)
{
    __shared__ float tile[64][65];
    const int bid = blockIdx.x;
    const int t = threadIdx.x;
    if (bid < 256) {
        const int b = bid >> 5, which = (bid >> 4) & 1, rtile = bid & 15;
        const int r0 = rtile << 3;
        const float* ctab = which ? cx : cy;
        const float* Wb = W + (size_t)(b * 1028 + (which ? 128 : 0)) * 256;
        float acc[8];
        #pragma unroll
        for (int r = 0; r < 8; r++) acc[r] = 0.f;
        for (int k = 0; k < 128; k++) {
            const float wv = Wb[(k << 8) + t];
            #pragma unroll
            for (int r = 0; r < 8; r++)
                acc[r] = fmaf(ctab[((r0 + r) << 7) + k], wv, acc[r]);
        }
        const float b1v = which ? 0.f : W[(size_t)(b * 1028 + 256) * 256 + t];
        f16* dst = which ? bxF : ayF;
        for (int r = 0; r < 8; r++)
            dst[(size_t)((b << 7) + r0 + r) * 256 + t] = (f16)((acc[r] + b1v) * SA_A);
        return;
    }
    const int id = bid - 256;                  // 384 = 8b * 3jj * 16 tiles
    const int b = id / 48;
    const int rr = id % 48;
    const int jj = rr / 16;
    const int tt = rr % 16;
    const int kt = tt >> 2, wt = tt & 3;
    const int k0 = kt << 6, n0 = wt << 6;
    const float* src = W + (size_t)(b * 1028 + 257 * (jj + 1)) * 256;
    for (int i = 0; i < 16; i++) {
        int e = i * 256 + t;
        int kk = e >> 6, nn = e & 63;
        tile[kk][nn] = src[(size_t)(k0 + kk) * 256 + n0 + nn];
    }
    __syncthreads();
    f16* dst = wjT + (size_t)(b * 3 + jj) * 65536;
    #pragma unroll
    for (int i = 0; i < 2; i++) {
        const int g = i * 256 + t;
        const int c_rel = g >> 8, sub = g & 255;
        const int nt = sub >> 6, ln = sub & 63;
        const int nl = ln & 15, q4g = ln >> 4;
        f16x8 v;
        #pragma unroll
        for (int ko = 0; ko < 8; ko++)
            v[ko] = (f16)(tile[(c_rel << 5) + (q4g << 3) + ko][(nt << 4) + nl] * SW_W);
        const int c = (kt << 1) + c_rel;
        *(f16x8*)(dst + (size_t)(((((c << 2) | wt) << 2) | nt) << 9) + (ln << 3)) = v;
    }
}

// ---- fused MLP: layers 2..4 + final projection + silu ----
// Converged structure (best measured): 256 thr / 4 waves, wave owns 64px x 64n,
// depth-2 persistent weight double-buffer from L2 (XCD-local via b=blk&7),
// non-draining raw barriers, packed f32->f16 cvt. Wave issue-slots saturated
// (MfmaUtil ~30% + VALUBusy ~39% + LDS + waitcnt); deeper pipelining spills,
// more occupancy starves registers, bigger tiles starve latency-hiding.
__global__ __launch_bounds__(256, 3) void k_main(
    const f16* __restrict__ wjT, const float* __restrict__ Wfull,
    const f16* __restrict__ ayF, const f16* __restrict__ bxF,
    const f16* __restrict__ lwf, const float* __restrict__ lb,
    const float* __restrict__ pa_p, float* __restrict__ out)
{
    __shared__ __align__(16) unsigned char actS[32768];     // 64px x 256f f16, slot-swizzled
    const int t = threadIdx.x;
    const int lane = t & 63;
    const int wc = t >> 6;
    const int nlo = lane & 15, q4 = lane >> 4;
    const int blk = blockIdx.x;
    const int b = blk & 7, rt = blk >> 3;      // batch = XCD index -> L2-local weights
    const int p0 = rt << 6;
    const int y = p0 >> 7, x0 = p0 & 127;
    const float pa = pa_p[0];

    const f16* wl0 = wjT + (size_t)(b * 3) * 65536;
    auto loadBg = [&](f16x8* dstv, int g) {
        const f16* p = wl0 + (size_t)(g >> 3) * 65536 + ((size_t)((((g & 7) << 2) | wc)) << 11) + (lane << 3);
        #pragma unroll
        for (int nt = 0; nt < 4; nt++) dstv[nt] = *(const f16x8*)(p + (nt << 9));
    };
    auto lbar = [&]() {      // LDS-drained barrier; vmem prefetch stays in flight
        asm volatile("s_waitcnt lgkmcnt(0)" ::: "memory");
        __builtin_amdgcn_s_barrier();
        __builtin_amdgcn_sched_barrier(0);
    };
    auto prelu4pk = [&](const f32x4 a, const f32x4 bsc) -> f16x4 {
        float v0 = fmaf(a[0], INV_SW, bsc[0]);
        float v1 = fmaf(a[1], INV_SW, bsc[1]);
        float v2 = fmaf(a[2], INV_SW, bsc[2]);
        float v3 = fmaf(a[3], INV_SW, bsc[3]);
        v0 = fmaxf(v0, 0.f) + pa * fminf(v0, 0.f);
        v1 = fmaxf(v1, 0.f) + pa * fminf(v1, 0.f);
        v2 = fmaxf(v2, 0.f) + pa * fminf(v2, 0.f);
        v3 = fmaxf(v3, 0.f) + pa * fminf(v3, 0.f);
        f16x2 lo = pkrtz(v0, v1);
        f16x2 hi = pkrtz(v2, v3);
        f16x4 r;
        r[0] = lo[0]; r[1] = lo[1]; r[2] = hi[0]; r[3] = hi[1];
        return r;
    };

    f16x8 bfA[4], bfB[4];
    loadBg(bfA, 0);          // persistent cross-layer weight double-buffer

    // ---- init act = f16(prelu(ayF[y] + bxF[x])), packed cvt ----
    {
        const int r = t & 63, g8 = t >> 6;
        const f16* ayr = ayF + (size_t)((b << 7) + y) * 256;
        const f16* bxr = bxF + (size_t)((b << 7) + x0 + r) * 256;
        const int rx = r & 7;
        #pragma unroll
        for (int mm = 0; mm < 8; mm++) {
            const int slot = (g8 << 3) + mm;
            const int f0 = slot << 3;
            f16x8 av = *(const f16x8*)(ayr + f0);
            f16x8 bv = *(const f16x8*)(bxr + f0);
            f16x8 v;
            #pragma unroll
            for (int i2 = 0; i2 < 4; i2++) {
                float h0 = (float)av[2 * i2] + (float)bv[2 * i2];
                float h1 = (float)av[2 * i2 + 1] + (float)bv[2 * i2 + 1];
                h0 = fmaxf(h0, 0.f) + pa * fminf(h0, 0.f);
                h1 = fmaxf(h1, 0.f) + pa * fminf(h1, 0.f);
                f16x2 pk2 = pkrtz(h0, h1);
                v[2 * i2] = pk2[0]; v[2 * i2 + 1] = pk2[1];
            }
            *(f16x8*)(actS + (r << 9) + ((slot ^ rx) << 4)) = v;
        }
    }
    lbar();

    for (int jj = 0; jj < 3; jj++) {
        const float* bias = Wfull + (size_t)(b * 1028 + 257 * (jj + 1) + 256) * 256;
        f32x4 bias4[4];
        #pragma unroll
        for (int nt = 0; nt < 4; nt++) {
            bias4[nt] = *(const f32x4*)(bias + (wc << 6) + (nt << 4) + (q4 << 2));
            bias4[nt] *= SA_A;
        }

        f32x4 acc[4][4];
        #pragma unroll
        for (int pt = 0; pt < 4; pt++)
            #pragma unroll
            for (int nt = 0; nt < 4; nt++) acc[pt][nt] = zero4();

        #pragma unroll
        for (int c = 0; c < 8; c++) {
            const int g = jj * 8 + c;
            f16x8* curW = (c & 1) ? bfB : bfA;     // g&1 == c&1 (jj*8 even)
            f16x8* nxtW = (c & 1) ? bfA : bfB;
            if (g < 23) loadBg(nxtW, g + 1);       // crosses layer boundary at c==7
            const int sl = (c << 2) + q4;
            f16x8 af[4];
            #pragma unroll
            for (int pt = 0; pt < 4; pt++) {
                const int rr = (pt << 4) + nlo;
                af[pt] = *(const f16x8*)(actS + (rr << 9) + ((sl ^ (rr & 7)) << 4));
            }
            #pragma unroll
            for (int pt = 0; pt < 4; pt++)
                #pragma unroll
                for (int nt = 0; nt < 4; nt++)
                    acc[pt][nt] = MFMA16(curW[nt], af[pt], acc[pt][nt]);
        }
        lbar();   // all reads of actS done (LDS only; vmem prefetch survives)

        // epilogue: act <- f16(prelu(acc/SW + SA*b_j)); packed cvt, 8B writes
        #pragma unroll
        for (int nt = 0; nt < 4; nt++) {
            const int nb = (wc << 6) + (nt << 4) + (q4 << 2);
            #pragma unroll
            for (int pt = 0; pt < 4; pt++) {
                const int rr = (pt << 4) + nlo;
                f16x4 pk = prelu4pk(acc[pt][nt], bias4[nt]);
                *(f16x4*)(actS + (rr << 9) + (((nb >> 3) ^ (rr & 7)) << 4) + ((nb & 7) << 1)) = pk;
            }
        }
        lbar();
    }

    // ---- final 256->3 projection + silu: each wave owns one 16-px tile ----
    {
        f32x4 acc2 = zero4();
        const int rr = (wc << 4) + nlo;
        #pragma unroll
        for (int c = 0; c < 8; c++) {
            const int sl = (c << 2) + q4;
            const f16x8 af = *(const f16x8*)(actS + (rr << 9) + ((sl ^ (rr & 7)) << 4));
            const f16x8 lf = *(const f16x8*)(lwf + (((c << 6) + lane) << 3));
            acc2 = MFMA16(af, lf, acc2);
        }
        if (nlo < 3) {
            const float lbv = lb[nlo];
            float* ob = out + ((size_t)(b * 3 + nlo) << 14) + p0 + (wc << 4) + (q4 << 2);
            #pragma unroll
            for (int i = 0; i < 4; i++) {
                float z = acc2[i] * INV_SASW + lbv;
                ob[i] = z / (1.f + expf(-z));
            }
        }
    }
}

extern "C" void kernel_launch(void* const* d_in, const int* in_sizes, int n_in,
                              void* d_out, int out_size, void* d_ws, size_t ws_size,
                              hipStream_t stream)
{
    (void)in_sizes; (void)n_in; (void)out_size; (void)ws_size;
    const float* x       = (const float*)d_in[0];
    const float* conv_w  = (const float*)d_in[1];
    const float* conv_b  = (const float*)d_in[2];
    const float* wfine_w = (const float*)d_in[3];
    const float* wfine_b = (const float*)d_in[4];
    const float* last1_w = (const float*)d_in[5];
    const float* last1_b = (const float*)d_in[6];
    const float* prelu_a = (const float*)d_in[7];
    char* ws = (char*)d_ws;
    float* Cy  = (float*)(ws + OFF_CY);
    float* Cx  = (float*)(ws + OFF_CX);
    f16*   lwf = (f16*)(ws + OFF_LW);
    float* S   = (float*)(ws + OFF_S);
    f16*   cw16= (f16*)(ws + OFF_CW);
    f16*   M2  = (f16*)(ws + OFF_M2);
    float* W   = (float*)(ws + OFF_W);
    f16*   AyF = (f16*)(ws + OFF_AY);
    f16*   BxF = (f16*)(ws + OFF_BX);
    f16*   wjT = (f16*)(ws + OFF_WT);

    k_prepA<<<1187, 256, 0, stream>>>(x, wfine_w, M2, Cy, Cx, lwf, last1_w, conv_w, cw16, S);
    k_gemmB<<<544, 256, 0, stream>>>(cw16, M2, conv_b, S, wfine_b, W);
    k_wprep<<<640, 256, 0, stream>>>(Cy, Cx, W, AyF, BxF, wjT);
    k_main<<<2048, 256, 0, stream>>>(wjT, W, AyF, BxF, lwf, last1_b, prelu_a, (float*)d_out);
}